// Round 15
// baseline (1285.911 us; speedup 1.0000x reference)
//
#include <hip/hip_runtime.h>
#include <hip/hip_bf16.h>

// Problem constants: B=256, T=512, D=64, H=256, C=10
#define Tt  512
#define Dd  64
#define CC  10

typedef short  short8 __attribute__((ext_vector_type(8)));
typedef __bf16 bf16x8 __attribute__((ext_vector_type(8)));
typedef float  f32x4  __attribute__((ext_vector_type(4)));
typedef int    int4v  __attribute__((ext_vector_type(4)));

__device__ __forceinline__ unsigned short f2bf(float f) {
    unsigned u = __builtin_bit_cast(unsigned, f);
    u += 0x7fffu + ((u >> 16) & 1u);   // RNE
    return (unsigned short)(u >> 16);
}
__device__ __forceinline__ float bf2f(unsigned short s) {
    unsigned u = ((unsigned)s) << 16;
    return __builtin_bit_cast(float, u);
}
__device__ __forceinline__ float sigf(float x) {
    return __builtin_amdgcn_rcpf(1.0f + __expf(-x));
}
__device__ __forceinline__ float tanh_fast(float x) {
    return 1.0f - 2.0f * __builtin_amdgcn_rcpf(1.0f + __expf(2.0f * x));
}

// ---------------------------------------------------------------------------
// Pre-permute weights into per-lane MFMA A-fragment order (bf16).
// elem index = ((nf*10 + ks)*64 + lane)*8 + j
//   nf = h16*4 + gate;  k = ks*32 + (lane>>4)*8 + j  (k<256 -> W_hh else W_ih)
//   row = lane&15 -> n_orig = gate*256 + h16*16 + row
// ---------------------------------------------------------------------------
__global__ void prep_weights(const float* __restrict__ W_ih,
                             const float* __restrict__ W_hh,
                             unsigned short* __restrict__ Wc) {
    int id = blockIdx.x * blockDim.x + threadIdx.x;   // 0 .. 327679
    int j    = id & 7;
    int lane = (id >> 3) & 63;
    int rest = id >> 9;            // 0..639
    int ks   = rest % 10;
    int nf   = rest / 10;
    int k    = ks * 32 + ((lane >> 4) << 3) + j;
    int row  = lane & 15;
    int h16  = nf >> 2;
    int g    = nf & 3;
    int n_orig = g * 256 + h16 * 16 + row;
    float v = (k < 256) ? W_hh[n_orig * 256 + k]
                        : W_ih[n_orig * 64 + (k - 256)];
    Wc[id] = f2bf(v);
}

// biasp[h16*64+g*16+i] = b_ih[n]+b_hh[n];  rsum[same] = sum_k W_hh[n,k]
// (rsum is the algebraic correction for the sign-tag bias on stored h.)
__global__ void prep_bias_rs(const float* __restrict__ b_ih,
                             const float* __restrict__ b_hh,
                             const float* __restrict__ W_hh,
                             float* __restrict__ biasp,
                             float* __restrict__ rsum) {
    int tid = blockIdx.x * blockDim.x + threadIdx.x;  // 1024 threads
    if (tid < 1024) {
        int h16 = tid >> 6, g = (tid >> 4) & 3, i = tid & 15;
        int n_orig = g * 256 + h16 * 16 + i;
        biasp[tid] = b_ih[n_orig] + b_hh[n_orig];
        float s = 0.f;
        for (int k = 0; k < 256; ++k) s += W_hh[n_orig * 256 + k];
        rsum[tid] = s;
    }
}

// ---------------------------------------------------------------------------
// Persistent LSTM, transposed GEMM (Z^T = W_cat @ [s;x]),  FLAG-FREE.
// Grid 64 WGs = 16 batch-groups (16 rows) x 4 hidx-parts. Wave w of WG(bg,p)
// owns h16 = p*4+w. Producer stores s_t = h_t + sigma_t (sigma alternates
// sign every 2 steps = per-buffer-write) via u64 agent atomic exchange; the
// SIGN BIT of every stored bf16 encodes freshness (|h|<1). Consumer
// speculatively re-issues ONE fused 8-load block (sc0 sc1 -> MALL) and
// validates one sign bit per u64 (= per swap unit); wave-__all gates use.
// Bias corrected algebraically: acc_init = bias - sigma_t * rowsum(W_hh).
// No fence, no flag, no barrier in the loop. Double-buffer lag invariant:
// publishing s_{t+1} requires having validated ALL of s_t, which proves all
// peers consumed s_{t-1} -> overwrite is safe.
// ---------------------------------------------------------------------------
__global__ __launch_bounds__(256, 1) void lstm_persist(
    const float* __restrict__ x,
    const unsigned short* __restrict__ Wc,
    const float* __restrict__ biasp,
    const float* __restrict__ rsum,
    unsigned short* __restrict__ h0buf,   // [256 batch][256 hidx] bf16 (biased)
    unsigned short* __restrict__ h1buf,
    const float* __restrict__ W_out,
    const float* __restrict__ b_out,
    float* __restrict__ out)
{
    const int tid  = threadIdx.x;
    const int lane = tid & 63;
    const int w    = tid >> 6;
    const int bg   = blockIdx.x & 15;   // batch group 0..15
    const int p    = blockIdx.x >> 4;   // hidx part  0..3
    const int l15  = lane & 15;
    const int lhi  = lane >> 4;

    const int h16   = p * 4 + w;        // 0..15 (16-hidx chunk)
    const int batch = bg * 16 + l15;    // this lane's batch column

    const float* xrow = x + (size_t)batch * (Tt * Dd) + lhi * 8;

    // --- weights + bias + rowsum (plain cached loads; L2 stays warm) -------
    bf16x8 wfrag[10][4];
    #pragma unroll
    for (int ks = 0; ks < 10; ++ks)
        #pragma unroll
        for (int g = 0; g < 4; ++g)
            wfrag[ks][g] = __builtin_bit_cast(bf16x8,
                *reinterpret_cast<const short8*>(
                    Wc + (((h16 * 4 + g) * 10 + ks) * 64 + lane) * 8));
    f32x4 bias_r[4], rs_r[4];
    #pragma unroll
    for (int g = 0; g < 4; ++g) {
        bias_r[g] = __builtin_bit_cast(f32x4,
            *reinterpret_cast<const float4*>(biasp + h16 * 64 + g * 16 + lhi * 4));
        rs_r[g] = __builtin_bit_cast(f32x4,
            *reinterpret_cast<const float4*>(rsum + h16 * 64 + g * 16 + lhi * 4));
    }

    // x(t=0)
    float4 xq0 = *reinterpret_cast<const float4*>(xrow);
    float4 xq1 = *reinterpret_cast<const float4*>(xrow + 4);
    float4 xq2 = *reinterpret_cast<const float4*>(xrow + 32);
    float4 xq3 = *reinterpret_cast<const float4*>(xrow + 36);

    f32x4 creg = (f32x4){0.f, 0.f, 0.f, 0.f};

    for (int t = 0; t < Tt; ++t) {
        const unsigned wantNeg = (unsigned)((t >> 1) & 1);  // sigma_t<0 ?
        // acc init with algebraic bias correction: bias - sigma_t*rsum
        float corr = (t == 0) ? 0.0f : (wantNeg ? 1.0f : -1.0f);  // -sigma_t
        f32x4 corrv = (f32x4){corr, corr, corr, corr};
        f32x4 acc[4];
        #pragma unroll
        for (int g = 0; g < 4; ++g) acc[g] = bias_r[g] + corrv * rs_r[g];

        // 1) x contribution
        {
            short8 a8 = (short8){ (short)f2bf(xq0.x), (short)f2bf(xq0.y),
                                  (short)f2bf(xq0.z), (short)f2bf(xq0.w),
                                  (short)f2bf(xq1.x), (short)f2bf(xq1.y),
                                  (short)f2bf(xq1.z), (short)f2bf(xq1.w) };
            short8 a9 = (short8){ (short)f2bf(xq2.x), (short)f2bf(xq2.y),
                                  (short)f2bf(xq2.z), (short)f2bf(xq2.w),
                                  (short)f2bf(xq3.x), (short)f2bf(xq3.y),
                                  (short)f2bf(xq3.z), (short)f2bf(xq3.w) };
            bf16x8 bv8 = __builtin_bit_cast(bf16x8, a8);
            bf16x8 bv9 = __builtin_bit_cast(bf16x8, a9);
            #pragma unroll
            for (int g = 0; g < 4; ++g) {
                acc[g] = __builtin_amdgcn_mfma_f32_16x16x32_bf16(wfrag[8][g], bv8, acc[g], 0, 0, 0);
                acc[g] = __builtin_amdgcn_mfma_f32_16x16x32_bf16(wfrag[9][g], bv9, acc[g], 0, 0, 0);
            }
        }

        // 2) validated speculative load of s_t (8 parallel MALL loads/iter)
        if (t > 0) {
            const unsigned short* hin = (t & 1) ? h1buf : h0buf;
            const void* haddr = hin + batch * 256 + lhi * 8;  // 16B aligned
            int4v v0, v1, v2, v3, v4, v5, v6, v7;
            for (;;) {
                asm volatile(
                    "global_load_dwordx4 %0, %8, off sc0 sc1\n\t"
                    "global_load_dwordx4 %1, %8, off offset:64 sc0 sc1\n\t"
                    "global_load_dwordx4 %2, %8, off offset:128 sc0 sc1\n\t"
                    "global_load_dwordx4 %3, %8, off offset:192 sc0 sc1\n\t"
                    "global_load_dwordx4 %4, %8, off offset:256 sc0 sc1\n\t"
                    "global_load_dwordx4 %5, %8, off offset:320 sc0 sc1\n\t"
                    "global_load_dwordx4 %6, %8, off offset:384 sc0 sc1\n\t"
                    "global_load_dwordx4 %7, %8, off offset:448 sc0 sc1\n\t"
                    "s_waitcnt vmcnt(0)"
                    : "=&v"(v0), "=&v"(v1), "=&v"(v2), "=&v"(v3),
                      "=&v"(v4), "=&v"(v5), "=&v"(v6), "=&v"(v7)
                    : "v"(haddr)
                    : "memory");
                // one sign bit per u64 swap-unit (bit 31 of .y / .w dwords)
                unsigned bad = 0;
                bad |= (((unsigned)v0.y >> 31) ^ wantNeg) | (((unsigned)v0.w >> 31) ^ wantNeg);
                bad |= (((unsigned)v1.y >> 31) ^ wantNeg) | (((unsigned)v1.w >> 31) ^ wantNeg);
                bad |= (((unsigned)v2.y >> 31) ^ wantNeg) | (((unsigned)v2.w >> 31) ^ wantNeg);
                bad |= (((unsigned)v3.y >> 31) ^ wantNeg) | (((unsigned)v3.w >> 31) ^ wantNeg);
                bad |= (((unsigned)v4.y >> 31) ^ wantNeg) | (((unsigned)v4.w >> 31) ^ wantNeg);
                bad |= (((unsigned)v5.y >> 31) ^ wantNeg) | (((unsigned)v5.w >> 31) ^ wantNeg);
                bad |= (((unsigned)v6.y >> 31) ^ wantNeg) | (((unsigned)v6.w >> 31) ^ wantNeg);
                bad |= (((unsigned)v7.y >> 31) ^ wantNeg) | (((unsigned)v7.w >> 31) ^ wantNeg);
                if (!__any((int)bad)) break;
            }
            int4v hvv[8] = { v0, v1, v2, v3, v4, v5, v6, v7 };
            #pragma unroll
            for (int ks = 0; ks < 8; ++ks) {
                bf16x8 bv = __builtin_bit_cast(bf16x8, hvv[ks]);
                #pragma unroll
                for (int g = 0; g < 4; ++g)
                    acc[g] = __builtin_amdgcn_mfma_f32_16x16x32_bf16(
                        wfrag[ks][g], bv, acc[g], 0, 0, 0);
            }
        }

        // 3) gates + c/h update; store s_{t+1} = h_{t+1} + sigma_{t+1}
        unsigned short* hout = ((t + 1) & 1) ? h1buf : h0buf;
        const float bnext = (((t + 1) >> 1) & 1) ? -1.0f : 1.0f;  // sigma_{t+1}
        unsigned long long hpack = 0;
        #pragma unroll
        for (int r = 0; r < 4; ++r) {
            float cn = sigf(acc[1][r]) * creg[r] + sigf(acc[0][r]) * tanh_fast(acc[2][r]);
            float hn = sigf(acc[3][r]) * tanh_fast(cn);
            creg[r] = cn;
            hpack |= (unsigned long long)f2bf(hn + bnext) << (16 * r);
        }
        {
            unsigned long long* hp = reinterpret_cast<unsigned long long*>(
                hout + batch * 256 + h16 * 16 + lhi * 4);
            (void)__hip_atomic_exchange(hp, hpack, __ATOMIC_RELAXED,
                                        __HIP_MEMORY_SCOPE_AGENT);
        }

        // 4) prefetch x for t+1 (plain cached, compiler-tracked)
        if (t + 1 < Tt) {
            const float* xp = xrow + (size_t)(t + 1) * Dd;
            xq0 = *reinterpret_cast<const float4*>(xp);
            xq1 = *reinterpret_cast<const float4*>(xp + 4);
            xq2 = *reinterpret_cast<const float4*>(xp + 32);
            xq3 = *reinterpret_cast<const float4*>(xp + 36);
        }
        // no barrier, no fence, no flag — validity travels with the data
    }

    // --- output head: p==0 WGs handle their 16 batches ----------------------
    // h_512 lives in buf0 with sigma_512 = +1 (sign bit 0). Validate per-u64.
    if (p == 0) {
        #pragma unroll 1
        for (int rr = 0; rr < 4; ++rr) {
            int row = bg * 16 + w * 4 + rr;
            const void* haddr = h0buf + row * 256 + lane * 4;  // one u64
            unsigned long long hu;
            for (;;) {
                asm volatile(
                    "global_load_dwordx2 %0, %1, off sc0 sc1\n\ts_waitcnt vmcnt(0)"
                    : "=&v"(hu) : "v"(haddr) : "memory");
                if (!__any((int)(hu >> 63))) break;   // expect sign +
            }
            float f0 = bf2f((unsigned short)(hu & 0xffff)) - 1.0f;
            float f1 = bf2f((unsigned short)((hu >> 16) & 0xffff)) - 1.0f;
            float f2 = bf2f((unsigned short)((hu >> 32) & 0xffff)) - 1.0f;
            float f3 = bf2f((unsigned short)(hu >> 48)) - 1.0f;
            #pragma unroll 1
            for (int cls = 0; cls < CC; ++cls) {
                float4 wv = *reinterpret_cast<const float4*>(W_out + cls * 256 + lane * 4);
                float pr = f0 * wv.x + f1 * wv.y + f2 * wv.z + f3 * wv.w;
                #pragma unroll
                for (int off = 32; off > 0; off >>= 1) pr += __shfl_down(pr, off);
                if (lane == 0) out[row * CC + cls] = sigf(pr + b_out[cls]);
            }
        }
    }
}

extern "C" void kernel_launch(void* const* d_in, const int* in_sizes, int n_in,
                              void* d_out, int out_size, void* d_ws, size_t ws_size,
                              hipStream_t stream) {
    const float* x     = (const float*)d_in[0];
    const float* W_ih  = (const float*)d_in[1];
    const float* W_hh  = (const float*)d_in[2];
    const float* b_ih  = (const float*)d_in[3];
    const float* b_hh  = (const float*)d_in[4];
    const float* W_out = (const float*)d_in[5];
    const float* b_out = (const float*)d_in[6];
    float* out = (float*)d_out;

    // workspace layout (~926 KB)
    char* ws = (char*)d_ws;
    unsigned short* Wc    = (unsigned short*)(ws);            // 655360 B
    float*          biasp = (float*)(ws + 655360);            //   4096 B
    float*          rsum  = (float*)(ws + 659456);            //   4096 B
    unsigned short* h0    = (unsigned short*)(ws + 663552);   // 131072 B
    unsigned short* h1    = (unsigned short*)(ws + 794624);   // 131072 B

    hipLaunchKernelGGL(prep_weights, dim3(1280), dim3(256), 0, stream, W_ih, W_hh, Wc);
    hipLaunchKernelGGL(prep_bias_rs, dim3(4),    dim3(256), 0, stream,
                       b_ih, b_hh, W_hh, biasp, rsum);
    // init tags: buf0 must read as sign+ (rejected where sigma<0 expected),
    // buf1 as sign- (rejected at t=1 which expects +). Re-run each replay.
    hipMemsetAsync(h0, 0x3F, 131072, stream);   // bf16 0x3F3F > 0
    hipMemsetAsync(h1, 0xBF, 131072, stream);   // bf16 0xBFBF < 0

    hipLaunchKernelGGL(lstm_persist, dim3(64), dim3(256), 0, stream,
                       x, Wc, biasp, rsum, h0, h1, W_out, b_out, out);
}